// Round 1
// baseline (237.048 us; speedup 1.0000x reference)
//
#include <hip/hip_runtime.h>
#include <hip/hip_bf16.h>
#include <stdint.h>

typedef unsigned short u16;
typedef __attribute__((ext_vector_type(8))) short short8;
typedef __attribute__((ext_vector_type(4))) float float4v;

// RNE float->bf16
__device__ __forceinline__ u16 f2bf(float x) {
    union { float f; unsigned int u; } v; v.f = x;
    unsigned int r = v.u + 0x7fffu + ((v.u >> 16) & 1u);
    return (u16)(r >> 16);
}

__device__ __forceinline__ void ld_g2l16(const void* g, void* l) {
    __builtin_amdgcn_global_load_lds(
        (const __attribute__((address_space(1))) void*)g,
        (__attribute__((address_space(3))) void*)l, 16, 0, 0);
}

// ---------------- Pass 1: convert tables to bf16 + pack W1 into B-frag layout ----
// W1pack[kc][t][lane][j] = W1[kc*32 + (lane>>4)*8 + j][t*16 + (lane&15)]
__global__ __launch_bounds__(256) void conv_pack(
    const float* __restrict__ zs, const float* __restrict__ zt,
    const float* __restrict__ W1,
    u16* __restrict__ zs_b, u16* __restrict__ zt_b, u16* __restrict__ w1p,
    int n_zs8, int n_zt8)
{
    int id = blockIdx.x * 256 + threadIdx.x;
    if (id < n_zs8 + n_zt8) {
        const float* src; u16* dst; int i;
        if (id < n_zs8) { src = zs; dst = zs_b; i = id; }
        else            { src = zt; dst = zt_b; i = id - n_zs8; }
        const float4* p = (const float4*)src + (size_t)i * 2;
        float4 x = p[0], y = p[1];
        short8 o;
        o[0] = (short)f2bf(x.x); o[1] = (short)f2bf(x.y);
        o[2] = (short)f2bf(x.z); o[3] = (short)f2bf(x.w);
        o[4] = (short)f2bf(y.x); o[5] = (short)f2bf(y.y);
        o[6] = (short)f2bf(y.z); o[7] = (short)f2bf(y.w);
        *(short8*)(dst + (size_t)i * 8) = o;
    } else {
        int w = id - (n_zs8 + n_zt8);
        if (w < 4096) {
            int lanep = w & 63, t = (w >> 6) & 7, kc = w >> 9;
            short8 o;
#pragma unroll
            for (int j = 0; j < 8; ++j) {
                int k = kc * 32 + (lanep >> 4) * 8 + j;
                int n = t * 16 + (lanep & 15);
                o[j] = (short)f2bf(W1[k * 128 + n]);
            }
            *(short8*)(w1p + (size_t)w * 8) = o;
        }
    }
}

// ---------------- Pass 2: gathered MFMA GEMM + fused MLP epilogue ----------------
// Block: 256 thr (4 waves), 128 edges. Wave (mh,nh) owns edges [64*mh,+64) x n [64*nh,+64).
// A-tile LDS: 128 edges x 512 B (concat row), 16B chunks XOR-swizzled by (edge&7).
__global__ __launch_bounds__(256, 2) void edge_mlp(
    const u16* __restrict__ zs, const u16* __restrict__ zt,
    const u16* __restrict__ w1p,
    const int* __restrict__ row, const int* __restrict__ col,
    const float* __restrict__ b1, const float* __restrict__ W2,
    const float* __restrict__ b2, float* __restrict__ out, int E)
{
    __shared__ u16 Atile[128 * 256];   // 64 KB exactly

    const int tid  = threadIdx.x;
    const int wave = tid >> 6, lane = tid & 63;
    const int mh = wave >> 1, nh = wave & 1;
    const int m15 = lane & 15, quad = lane >> 4;
    const int blockbase = blockIdx.x * 128;

    // B fragments (register-resident, same for all blocks; served from L1/L2)
    float b1v[4], w2v[4];
    short8 Bfr[8][4];
    {
        int ncol = (nh << 6) + m15;
#pragma unroll
        for (int ntl = 0; ntl < 4; ++ntl) {
            b1v[ntl] = b1[ncol + ntl * 16];
            w2v[ntl] = W2[ncol + ntl * 16];
        }
#pragma unroll
        for (int kc = 0; kc < 8; ++kc)
#pragma unroll
            for (int ntl = 0; ntl < 4; ++ntl) {
                int t = (nh << 2) + ntl;
                Bfr[kc][ntl] = *(const short8*)(w1p + (size_t)((kc * 8 + t) * 64 + lane) * 8);
            }
    }
    const float b2v = b2[0];

    // ---- stage A-tile: each wave gathers edges [wave*32, +32), 2 edges per issue ----
    {
        const int half = (lane >> 4) & 1;      // 0: z_start half, 1: z_to half
        const u16* table = half ? zt : zs;
#pragma unroll
        for (int it = 0; it < 16; ++it) {
            int el = (wave << 5) + (it << 1) + (lane >> 5);
            int eg = blockbase + el; if (eg >= E) eg = E - 1;
            int idx = half ? col[eg] : row[eg];
            int src_chunk = m15 ^ (el & 7);    // XOR swizzle on the SOURCE side
            const char* gptr = (const char*)table + ((size_t)(unsigned)idx << 8) + (src_chunk << 4);
            // wave-uniform LDS base; HW writes base + lane*16 (1 KB = 2 edges)
            char* lptr = (char*)Atile + (((wave << 5) + (it << 1)) << 9);
            ld_g2l16(gptr, lptr);
        }
    }
    __builtin_amdgcn_s_waitcnt(0);
    __syncthreads();

    // ---- MFMA: 4 m-tiles x 4 n-tiles x 8 k-chunks per wave ----
    float4v acc[4][4];
#pragma unroll
    for (int a = 0; a < 4; ++a)
#pragma unroll
        for (int b = 0; b < 4; ++b)
            acc[a][b] = (float4v){0.f, 0.f, 0.f, 0.f};

#pragma unroll
    for (int kc = 0; kc < 8; ++kc) {
#pragma unroll
        for (int mtl = 0; mtl < 4; ++mtl) {
            int e_row = (mh << 6) + (mtl << 4) + m15;
            int cg = (kc << 2) + quad;           // 16B-chunk index in 512B row
            int half = cg >> 4, cw = cg & 15;
            int cl = cw ^ (e_row & 7);           // undo swizzle
            short8 Afr = *(const short8*)(Atile + e_row * 256 + half * 128 + cl * 8);
#pragma unroll
            for (int ntl = 0; ntl < 4; ++ntl)
                acc[mtl][ntl] = __builtin_amdgcn_mfma_f32_16x16x32_bf16(
                    Afr, Bfr[kc][ntl], acc[mtl][ntl], 0, 0, 0);
        }
    }

    // ---- epilogue: +b1, relu, dot W2, reduce 16 lanes, cross-wave via LDS ----
    __syncthreads();                 // A-tile dead; reuse as obuf[2][128] floats
    float* obuf = (float*)Atile;

#pragma unroll
    for (int mtl = 0; mtl < 4; ++mtl) {
        float part[4];
#pragma unroll
        for (int r = 0; r < 4; ++r) {
            float s = 0.f;
#pragma unroll
            for (int ntl = 0; ntl < 4; ++ntl) {
                float h = acc[mtl][ntl][r] + b1v[ntl];
                h = h > 0.f ? h : 0.f;
                s = fmaf(h, w2v[ntl], s);
            }
            s += __shfl_xor(s, 1);
            s += __shfl_xor(s, 2);
            s += __shfl_xor(s, 4);
            s += __shfl_xor(s, 8);
            part[r] = s;
        }
        if (m15 == 0) {
            int ml = (mh << 6) + (mtl << 4) + (quad << 2);
            *(float4v*)(obuf + nh * 128 + ml) = (float4v){part[0], part[1], part[2], part[3]};
        }
    }
    __syncthreads();
    if (tid < 128) {
        int e = blockbase + tid;
        if (e < E) out[e] = obuf[tid] + obuf[128 + tid] + b2v;
    }
}

// ---------------- Fallback (fp32, slow but correct) if workspace too small -------
__global__ __launch_bounds__(256) void edge_mlp_naive(
    const float* __restrict__ zs, const float* __restrict__ zt,
    const int* __restrict__ row, const int* __restrict__ col,
    const float* __restrict__ W1, const float* __restrict__ b1,
    const float* __restrict__ W2, const float* __restrict__ b2,
    float* __restrict__ out, int E)
{
    __shared__ float zr[4][256];
    int wave = threadIdx.x >> 6, lane = threadIdx.x & 63;
    int e = blockIdx.x * 4 + wave;
    int ec = e < E ? e : E - 1;
    const float* a = zs + (size_t)row[ec] * 128;
    const float* bb = zt + (size_t)col[ec] * 128;
    zr[wave][lane] = a[lane];
    zr[wave][64 + lane] = a[64 + lane];
    zr[wave][128 + lane] = bb[lane];
    zr[wave][192 + lane] = bb[64 + lane];
    __syncthreads();
    float h0 = b1[lane], h1 = b1[64 + lane];
    for (int k = 0; k < 256; ++k) {
        float zk = zr[wave][k];
        h0 = fmaf(zk, W1[k * 128 + lane], h0);
        h1 = fmaf(zk, W1[k * 128 + 64 + lane], h1);
    }
    h0 = h0 > 0.f ? h0 : 0.f;
    h1 = h1 > 0.f ? h1 : 0.f;
    float s = fmaf(h0, W2[lane], h1 * W2[64 + lane]);
    for (int m = 1; m < 64; m <<= 1) s += __shfl_xor(s, m);
    if (lane == 0 && e < E) out[e] = s + b2[0];
}

extern "C" void kernel_launch(void* const* d_in, const int* in_sizes, int n_in,
                              void* d_out, int out_size, void* d_ws, size_t ws_size,
                              hipStream_t stream) {
    const float* zs = (const float*)d_in[0];
    const float* zt = (const float*)d_in[1];
    const int*  row = (const int*)d_in[2];
    const int*  col = (const int*)d_in[3];
    const float* W1 = (const float*)d_in[4];
    const float* b1 = (const float*)d_in[5];
    const float* W2 = (const float*)d_in[6];
    const float* b2 = (const float*)d_in[7];
    float* out = (float*)d_out;

    const int nzs = in_sizes[0];       // 12,800,000
    const int nzt = in_sizes[1];       // 6,400,000
    const int E   = in_sizes[2];       // 1,000,000

    const size_t need = ((size_t)nzs + (size_t)nzt + 32768) * 2;
    if (ws_size < need) {
        int nb = (E + 3) / 4;
        edge_mlp_naive<<<nb, 256, 0, stream>>>(zs, zt, row, col, W1, b1, W2, b2, out, E);
        return;
    }

    u16* zs_b = (u16*)d_ws;
    u16* zt_b = zs_b + nzs;
    u16* w1p  = zt_b + nzt;

    const int n_zs8 = nzs / 8, n_zt8 = nzt / 8;
    const int convN = n_zs8 + n_zt8 + 4096;
    conv_pack<<<(convN + 255) / 256, 256, 0, stream>>>(zs, zt, W1, zs_b, zt_b, w1p, n_zs8, n_zt8);

    const int nblocks = (E + 127) / 128;
    edge_mlp<<<nblocks, 256, 0, stream>>>(zs_b, zt_b, w1p, row, col, b1, W2, b2, out, E);
}